// Round 4
// baseline (215.687 us; speedup 1.0000x reference)
//
#include <hip/hip_runtime.h>

#define PEPS  1e-5f
#define LOG2E 1.4426950408889634f

__device__ __forceinline__ float fast_rcp(float x) { return __builtin_amdgcn_rcpf(x); }

// out = x * (0.5 + 0.5 * sigmoid((x-m)*rs)), with nrs2 = -rs*log2e, mrs = m*rs*log2e:
// sigmoid((x-m)rs) = 1/(1+exp2(fma(x,nrs2,mrs)))
__device__ __forceinline__ float patch_one(float x, float nrs2, float mrs) {
    const float e = __builtin_amdgcn_exp2f(fmaf(x, nrs2, mrs));
    return x * fmaf(0.5f, fast_rcp(1.0f + e), 0.5f);
}

__device__ __forceinline__ void wave_reduce2(float& a, float& b) {
#pragma unroll
    for (int off = 32; off; off >>= 1) {
        a += __shfl_xor(a, off);
        b += __shfl_xor(b, off);
    }
}

// One block per 128x256 HALF image (512 thr = 8 waves, one wave per 64x64 patch).
// Pass 1 (s=64) wave-local; pass 2 (s=128) block-local; pass 3 (s=256) via
// device-scope atomic handshake with the partner block in ws.
// launch_bounds(512, 2): r3's (512,4) capped VGPR at 60 -> spilled v[16] to
// scratch (dur 242us). (512,2) keeps the cap >= 128 under either 2nd-arg
// semantics; ~100 VGPR body -> no spill, 2 blocks/CU resident.
__global__ __launch_bounds__(512, 2) void fused_pyramid_half(
    const float* __restrict__ in, float* __restrict__ out, float* __restrict__ ws)
{
    constexpr int W = 256;
    const int tid  = threadIdx.x;
    const int wave = tid >> 6;          // 0..7 -> 2x4 grid of 64x64 patches
    const int lane = tid & 63;
    const int img  = blockIdx.x >> 1;
    const int half = blockIdx.x & 1;
    const int pr   = wave >> 2;         // 0..1
    const int pc   = wave & 3;          // 0..3
    const size_t base = (size_t)img * (W * W) + (size_t)half * (128 * W)
                      + (size_t)(pr * 64) * W + pc * 64;

    __shared__ float redS[8], redQ[8], stats[2];

    // ---- load (64 floats/lane) + pass-1 partial sums -----------------------
    float4 v[16];
    float s = 0.f, q = 0.f;
#pragma unroll
    for (int u = 0; u < 16; ++u) {
        const int j  = u * 64 + lane;
        const int r  = j >> 4;          // 16 float4 per 64-wide patch row
        const int c4 = j & 15;
        const float4 t = *reinterpret_cast<const float4*>(in + base + (size_t)r * W + c4 * 4);
        v[u] = t;
        s += (t.x + t.y) + (t.z + t.w);
        q = fmaf(t.x, t.x, fmaf(t.y, t.y, fmaf(t.z, t.z, fmaf(t.w, t.w, q))));
    }

    // ---- pass 1 (s=64): wave-local stats ------------------------------------
    wave_reduce2(s, q);
    float m  = s * (1.0f / 4096.0f);
    float rs = rsqrtf(fmaf(-m, m, q * (1.0f / 4096.0f)) + PEPS);
    float nrs2 = rs * -LOG2E;
    float mrs  = m * rs * LOG2E;

    float s2 = 0.f, q2 = 0.f;
#pragma unroll
    for (int u = 0; u < 16; ++u) {
        float4 t = v[u];
        t.x = patch_one(t.x, nrs2, mrs);
        t.y = patch_one(t.y, nrs2, mrs);
        t.z = patch_one(t.z, nrs2, mrs);
        t.w = patch_one(t.w, nrs2, mrs);
        v[u] = t;
        s2 += (t.x + t.y) + (t.z + t.w);
        q2 = fmaf(t.x, t.x, fmaf(t.y, t.y, fmaf(t.z, t.z, fmaf(t.w, t.w, q2))));
    }

    // ---- pass 2 (s=128): combine 2x2 waves via LDS --------------------------
    wave_reduce2(s2, q2);
    if (lane == 0) { redS[wave] = s2; redQ[wave] = q2; }
    __syncthreads();
    const int w00 = wave & ~5;          // clears pc bit0 (1) and pr bit0 (4)
    {
        const float S = (redS[w00] + redS[w00 + 1]) + (redS[w00 + 4] + redS[w00 + 5]);
        const float Q = (redQ[w00] + redQ[w00 + 1]) + (redQ[w00 + 4] + redQ[w00 + 5]);
        m  = S * (1.0f / 16384.0f);
        rs = rsqrtf(fmaf(-m, m, Q * (1.0f / 16384.0f)) + PEPS);
    }
    nrs2 = rs * -LOG2E;
    mrs  = m * rs * LOG2E;

    float s3 = 0.f, q3 = 0.f;
#pragma unroll
    for (int u = 0; u < 16; ++u) {
        float4 t = v[u];
        t.x = patch_one(t.x, nrs2, mrs);
        t.y = patch_one(t.y, nrs2, mrs);
        t.z = patch_one(t.z, nrs2, mrs);
        t.w = patch_one(t.w, nrs2, mrs);
        v[u] = t;
        s3 += (t.x + t.y) + (t.z + t.w);
        q3 = fmaf(t.x, t.x, fmaf(t.y, t.y, fmaf(t.z, t.z, fmaf(t.w, t.w, q3))));
    }

    // ---- pass 3 (s=256): block partial -> cross-block handshake -------------
    wave_reduce2(s3, q3);
    __syncthreads();                    // pass-2 partial reads all done
    if (lane == 0) { redS[wave] = s3; redQ[wave] = q3; }
    __syncthreads();
    if (tid == 0) {
        float S = 0.f, Q = 0.f;
#pragma unroll
        for (int w = 0; w < 8; ++w) { S += redS[w]; Q += redQ[w]; }
        float* slot = ws + (size_t)img * 4;        // {S, Q, flag, pad}
        atomicAdd(slot + 0, S);
        atomicAdd(slot + 1, Q);
        __threadfence();                           // partials visible before flag
        unsigned* flag = reinterpret_cast<unsigned*>(slot + 2);
        atomicAdd(flag, 1u);
        while (__hip_atomic_load(flag, __ATOMIC_ACQUIRE, __HIP_MEMORY_SCOPE_AGENT) < 2u)
            __builtin_amdgcn_s_sleep(1);
        const float St = __hip_atomic_load(slot + 0, __ATOMIC_RELAXED, __HIP_MEMORY_SCOPE_AGENT);
        const float Qt = __hip_atomic_load(slot + 1, __ATOMIC_RELAXED, __HIP_MEMORY_SCOPE_AGENT);
        const float mm = St * (1.0f / 65536.0f);
        stats[0] = mm;
        stats[1] = rsqrtf(fmaf(-mm, mm, Qt * (1.0f / 65536.0f)) + PEPS);
    }
    __syncthreads();
    m  = stats[0];
    rs = stats[1];
    nrs2 = rs * -LOG2E;
    mrs  = m * rs * LOG2E;

    // ---- apply pass 3 + store ----------------------------------------------
#pragma unroll
    for (int u = 0; u < 16; ++u) {
        const int j  = u * 64 + lane;
        const int r  = j >> 4;
        const int c4 = j & 15;
        float4 t = v[u];
        t.x = patch_one(t.x, nrs2, mrs);
        t.y = patch_one(t.y, nrs2, mrs);
        t.z = patch_one(t.z, nrs2, mrs);
        t.w = patch_one(t.w, nrs2, mrs);
        *reinterpret_cast<float4*>(out + base + (size_t)r * W + c4 * 4) = t;
    }
}

extern "C" void kernel_launch(void* const* d_in, const int* in_sizes, int n_in,
                              void* d_out, int out_size, void* d_ws, size_t ws_size,
                              hipStream_t stream)
{
    const float* x = (const float*)d_in[0];
    float* out = (float*)d_out;
    constexpr int IMGS = 16 * 64;       // b * c images of 256x256

    // Zero the handshake slots every call (graph-captured; keeps replays
    // deterministic — harness does NOT re-poison d_ws between replays).
    hipMemsetAsync(d_ws, 0, (size_t)IMGS * 4 * sizeof(float), stream);

    fused_pyramid_half<<<IMGS * 2, 512, 0, stream>>>(x, out, (float*)d_ws);
}

// Round 5
// 214.103 us; speedup vs baseline: 1.0074x; 1.0074x over previous
//
#include <hip/hip_runtime.h>

#define PEPS  1e-5f
#define LOG2E 1.4426950408889634f

__device__ __forceinline__ float fast_rcp(float x) { return __builtin_amdgcn_rcpf(x); }

// out = x * (0.5 + 0.5 * sigmoid((x-m)*rs)), with nrs2 = -rs*log2e, mrs = m*rs*log2e:
// sigmoid((x-m)rs) = 1/(1+exp2(fma(x,nrs2,mrs)))
__device__ __forceinline__ float patch_one(float x, float nrs2, float mrs) {
    const float e = __builtin_amdgcn_exp2f(fmaf(x, nrs2, mrs));
    return x * fmaf(0.5f, fast_rcp(1.0f + e), 0.5f);
}

__device__ __forceinline__ void wave_reduce2(float& a, float& b) {
#pragma unroll
    for (int off = 32; off; off >>= 1) {
        a += __shfl_xor(a, off);
        b += __shfl_xor(b, off);
    }
}

// One block per 128x256 HALF image (512 thr = 8 waves, one wave per 64x64 patch).
// Pass 1 (s=64) wave-local; pass 2 (s=128) block-local; pass 3 (s=256) via
// device-scope atomic handshake with the partner block in ws.
//
// Occupancy pinning: launch_bounds' 2nd arg is only a MIN waves/EU — r3/r4
// showed the compiler still targets 8 waves/EU and spills v[16] to scratch
// (VGPR_Count=60, 242us). amdgpu_waves_per_eu(4,4) pins min=max=4: 128-VGPR
// budget, no incentive to spill, 2 blocks/CU resident (load/store of one
// overlaps compute of the other).
__global__ __attribute__((amdgpu_flat_work_group_size(512, 512),
                          amdgpu_waves_per_eu(4, 4)))
void fused_pyramid_half(const float* __restrict__ in, float* __restrict__ out,
                        float* __restrict__ ws)
{
    constexpr int W = 256;
    const int tid  = threadIdx.x;
    const int wave = tid >> 6;          // 0..7 -> 2x4 grid of 64x64 patches
    const int lane = tid & 63;
    const int img  = blockIdx.x >> 1;
    const int half = blockIdx.x & 1;
    const int pr   = wave >> 2;         // 0..1
    const int pc   = wave & 3;          // 0..3
    const size_t base = (size_t)img * (W * W) + (size_t)half * (128 * W)
                      + (size_t)(pr * 64) * W + pc * 64;

    __shared__ float redS[8], redQ[8], stats[2];

    // ---- load (64 floats/lane) + pass-1 partial sums -----------------------
    float4 v[16];
    float s = 0.f, q = 0.f;
#pragma unroll
    for (int u = 0; u < 16; ++u) {
        const int j  = u * 64 + lane;
        const int r  = j >> 4;          // 16 float4 per 64-wide patch row
        const int c4 = j & 15;
        const float4 t = *reinterpret_cast<const float4*>(in + base + (size_t)r * W + c4 * 4);
        v[u] = t;
        s += (t.x + t.y) + (t.z + t.w);
        q = fmaf(t.x, t.x, fmaf(t.y, t.y, fmaf(t.z, t.z, fmaf(t.w, t.w, q))));
    }

    // ---- pass 1 (s=64): wave-local stats ------------------------------------
    wave_reduce2(s, q);
    float m  = s * (1.0f / 4096.0f);
    float rs = rsqrtf(fmaf(-m, m, q * (1.0f / 4096.0f)) + PEPS);
    float nrs2 = rs * -LOG2E;
    float mrs  = m * rs * LOG2E;

    float s2 = 0.f, q2 = 0.f;
#pragma unroll
    for (int u = 0; u < 16; ++u) {
        float4 t = v[u];
        t.x = patch_one(t.x, nrs2, mrs);
        t.y = patch_one(t.y, nrs2, mrs);
        t.z = patch_one(t.z, nrs2, mrs);
        t.w = patch_one(t.w, nrs2, mrs);
        v[u] = t;
        s2 += (t.x + t.y) + (t.z + t.w);
        q2 = fmaf(t.x, t.x, fmaf(t.y, t.y, fmaf(t.z, t.z, fmaf(t.w, t.w, q2))));
    }

    // ---- pass 2 (s=128): combine 2x2 waves via LDS --------------------------
    wave_reduce2(s2, q2);
    if (lane == 0) { redS[wave] = s2; redQ[wave] = q2; }
    __syncthreads();
    const int w00 = wave & ~5;          // clears pc bit0 (1) and pr bit0 (4)
    {
        const float S = (redS[w00] + redS[w00 + 1]) + (redS[w00 + 4] + redS[w00 + 5]);
        const float Q = (redQ[w00] + redQ[w00 + 1]) + (redQ[w00 + 4] + redQ[w00 + 5]);
        m  = S * (1.0f / 16384.0f);
        rs = rsqrtf(fmaf(-m, m, Q * (1.0f / 16384.0f)) + PEPS);
    }
    nrs2 = rs * -LOG2E;
    mrs  = m * rs * LOG2E;

    float s3 = 0.f, q3 = 0.f;
#pragma unroll
    for (int u = 0; u < 16; ++u) {
        float4 t = v[u];
        t.x = patch_one(t.x, nrs2, mrs);
        t.y = patch_one(t.y, nrs2, mrs);
        t.z = patch_one(t.z, nrs2, mrs);
        t.w = patch_one(t.w, nrs2, mrs);
        v[u] = t;
        s3 += (t.x + t.y) + (t.z + t.w);
        q3 = fmaf(t.x, t.x, fmaf(t.y, t.y, fmaf(t.z, t.z, fmaf(t.w, t.w, q3))));
    }

    // ---- pass 3 (s=256): block partial -> cross-block handshake -------------
    wave_reduce2(s3, q3);
    __syncthreads();                    // pass-2 partial reads all done
    if (lane == 0) { redS[wave] = s3; redQ[wave] = q3; }
    __syncthreads();
    if (tid == 0) {
        float S = 0.f, Q = 0.f;
#pragma unroll
        for (int w = 0; w < 8; ++w) { S += redS[w]; Q += redQ[w]; }
        float* slot = ws + (size_t)img * 4;        // {S, Q, flag, pad}
        atomicAdd(slot + 0, S);
        atomicAdd(slot + 1, Q);
        __threadfence();                           // partials visible before flag
        unsigned* flag = reinterpret_cast<unsigned*>(slot + 2);
        atomicAdd(flag, 1u);
        while (__hip_atomic_load(flag, __ATOMIC_ACQUIRE, __HIP_MEMORY_SCOPE_AGENT) < 2u)
            __builtin_amdgcn_s_sleep(1);
        const float St = __hip_atomic_load(slot + 0, __ATOMIC_RELAXED, __HIP_MEMORY_SCOPE_AGENT);
        const float Qt = __hip_atomic_load(slot + 1, __ATOMIC_RELAXED, __HIP_MEMORY_SCOPE_AGENT);
        const float mm = St * (1.0f / 65536.0f);
        stats[0] = mm;
        stats[1] = rsqrtf(fmaf(-mm, mm, Qt * (1.0f / 65536.0f)) + PEPS);
    }
    __syncthreads();
    m  = stats[0];
    rs = stats[1];
    nrs2 = rs * -LOG2E;
    mrs  = m * rs * LOG2E;

    // ---- apply pass 3 + store ----------------------------------------------
#pragma unroll
    for (int u = 0; u < 16; ++u) {
        const int j  = u * 64 + lane;
        const int r  = j >> 4;
        const int c4 = j & 15;
        float4 t = v[u];
        t.x = patch_one(t.x, nrs2, mrs);
        t.y = patch_one(t.y, nrs2, mrs);
        t.z = patch_one(t.z, nrs2, mrs);
        t.w = patch_one(t.w, nrs2, mrs);
        *reinterpret_cast<float4*>(out + base + (size_t)r * W + c4 * 4) = t;
    }
}

extern "C" void kernel_launch(void* const* d_in, const int* in_sizes, int n_in,
                              void* d_out, int out_size, void* d_ws, size_t ws_size,
                              hipStream_t stream)
{
    const float* x = (const float*)d_in[0];
    float* out = (float*)d_out;
    constexpr int IMGS = 16 * 64;       // b * c images of 256x256

    // Zero the handshake slots every call (graph-captured; keeps replays
    // deterministic — harness does NOT re-poison d_ws between replays).
    hipMemsetAsync(d_ws, 0, (size_t)IMGS * 4 * sizeof(float), stream);

    fused_pyramid_half<<<IMGS * 2, 512, 0, stream>>>(x, out, (float*)d_ws);
}